// Round 5
// baseline (116.458 us; speedup 1.0000x reference)
//
#include <hip/hip_runtime.h>
#include <hip/hip_bf16.h>

#define LEN   2048
#define KNB   32
#define HID   128

typedef unsigned long long ull;
typedef unsigned int uint32;
typedef __bf16 bf16x8 __attribute__((ext_vector_type(8)));
typedef float  f32x4  __attribute__((ext_vector_type(4)));

// ---------------------------------------------------------------------------
// Kernel 0: prep — pack CA coords + mask penalty as float4, convert W to bf16.
// ---------------------------------------------------------------------------
__global__ __launch_bounds__(256) void prep_kernel(
    const float* __restrict__ X, const float* __restrict__ mask,
    const float* __restrict__ W_edge,
    float4* __restrict__ CAm, __bf16* __restrict__ Wbf) {
    const int t = blockIdx.x * 256 + threadIdx.x;
    if (t < 2 * LEN) {
        const float* p = X + (size_t)t * 12;
        CAm[t] = make_float4(p[3], p[4], p[5],
                             __fmul_rn(__fsub_rn(1.0f, mask[t]), 1000000.0f));
    }
    Wbf[t] = (__bf16)W_edge[t];
}

// ---------------------------------------------------------------------------
// Kernel 1: exact top-K=32 via histogram-select (unchanged — working).
// ---------------------------------------------------------------------------
__global__ __launch_bounds__(256) void topk_kernel(
    const float4* __restrict__ CAm, float* __restrict__ eidx_out) {
    const int row = blockIdx.x;
    const int b = row >> 11;
    const int i = row & (LEN - 1);
    const int tid = threadIdx.x;

    __shared__ int hist[512];
    __shared__ ull cand[LEN];
    __shared__ int candcnt;
    __shared__ int selB;

    const float4* C = CAm + (size_t)b * LEN;
    const float4 ci = C[i];

    uint32 d2b[8];
#pragma unroll
    for (int q = 0; q < 8; ++q) {
        const float4 cj = C[q * 256 + tid];
        float dx = __fsub_rn(ci.x, cj.x);
        float dy = __fsub_rn(ci.y, cj.y);
        float dz = __fsub_rn(ci.z, cj.z);
        float d2 = __fadd_rn(__fadd_rn(__fmul_rn(dx, dx), __fmul_rn(dy, dy)),
                             __fmul_rn(dz, dz));
        d2 = __fadd_rn(d2, cj.w);
        d2b[q] = __float_as_uint(d2);
    }

    hist[tid] = 0; hist[tid + 256] = 0;
    if (tid == 0) candcnt = 0;
    __syncthreads();
#pragma unroll
    for (int q = 0; q < 8; ++q) atomicAdd(&hist[d2b[q] >> 22], 1);
    __syncthreads();

    if (tid < 64) {
        int loc[8];
        int s = 0;
#pragma unroll
        for (int t = 0; t < 8; ++t) { loc[t] = hist[tid * 8 + t]; s += loc[t]; }
        int incl = s;
#pragma unroll
        for (int off = 1; off < 64; off <<= 1) {
            int o = __shfl_up(incl, off, 64);
            if (tid >= off) incl += o;
        }
        const int excl = incl - s;
        if (excl < KNB && incl >= KNB) {
            int c = excl;
#pragma unroll
            for (int t = 0; t < 8; ++t) {
                int c2 = c + loc[t];
                if (c < KNB && c2 >= KNB) selB = tid * 8 + t;
                c = c2;
            }
        }
    }
    __syncthreads();
    const uint32 B = (uint32)selB;

#pragma unroll
    for (int q = 0; q < 8; ++q) {
        if ((d2b[q] >> 22) <= B) {
            int p = atomicAdd(&candcnt, 1);
            cand[p] = (((ull)d2b[q]) << 32) | (uint32)(q * 256 + tid);
        }
    }
    __syncthreads();
    const int M = candcnt;

    for (int c = tid; c < M; c += 256) {
        const ull k = cand[c];
        int r = 0;
        for (int m = 0; m < M; ++m) r += (cand[m] < k);
        if (r < KNB)
            eidx_out[(size_t)row * KNB + r] = (float)(uint32)(k & 0xFFFFFFFFull);
    }
}

// ---------------------------------------------------------------------------
// Kernel 2: 8 rows/block, 512 thr (8 waves). Wave w: W-slice (16 ch x K=416)
// register-resident. Per row: [zero-next-sbuf | GEMM | shfl-reduce partial
// sums | LDS-atomic accumulate] barrier [LN from registers + direct global
// store | next row's features] barrier. No hbuf, no scatter/re-read phase.
// ---------------------------------------------------------------------------
__device__ __forceinline__ void load_res_atoms(const float* __restrict__ p, float* dst) {
    const float Nx = p[0], Ny = p[1], Nz = p[2];
    const float Ax = p[3], Ay = p[4], Az = p[5];
    const float Cx = p[6], Cy = p[7], Cz = p[8];
    const float Ox = p[9], Oy = p[10], Oz = p[11];
    const float bx = Ax - Nx, by = Ay - Ny, bz = Az - Nz;
    const float cx = Cx - Ax, cy = Cy - Ay, cz = Cz - Az;
    const float axv = by * cz - bz * cy;
    const float ayv = bz * cx - bx * cz;
    const float azv = bx * cy - by * cx;
    dst[0] = Nx;  dst[1] = Ny;  dst[2] = Nz;
    dst[3] = Ax;  dst[4] = Ay;  dst[5] = Az;
    dst[6] = Cx;  dst[7] = Cy;  dst[8] = Cz;
    dst[9] = Ox;  dst[10] = Oy; dst[11] = Oz;
    dst[12] = -0.58273431f * axv + 0.56802827f * bx + -0.54067466f * cx + Ax;
    dst[13] = -0.58273431f * ayv + 0.56802827f * by + -0.54067466f * cy + Ay;
    dst[14] = -0.58273431f * azv + 0.56802827f * bz + -0.54067466f * cz + Az;
}

#define FSTRIDE 424   // bf16; dw-stride 212 % 32 = 20 -> only 2-way aliasing

__global__ __launch_bounds__(512, 6) void edge_kernel(
    const float* __restrict__ X,
    const int* __restrict__ Ridx, const int* __restrict__ Chain,
    const float* __restrict__ W_pos, const float* __restrict__ b_pos,
    const __bf16* __restrict__ Wbf,
    const float* __restrict__ lng, const float* __restrict__ lnb,
    const float* __restrict__ eidx_f, float* __restrict__ outE) {
    const int tid = threadIdx.x;
    const int row0 = blockIdx.x * 8;
    const int b = row0 >> 11;                 // 2048 % 8 == 0: no batch straddle
    const int i0 = row0 & (LEN - 1);

    __shared__ __align__(16) __bf16 featE[32 * FSTRIDE];  // 27136 B
    __shared__ float natoms8[8][32][17];                  // 17408 B
    __shared__ float iatoms8[8][16];                      //   512 B
    __shared__ int jR8[8][32], jC8[8][32];                //  2048 B
    __shared__ float sbuf[2][64];                         //   512 B: [par][e*2+{s,q}]

    const float* Xb = X + (size_t)b * LEN * 12;

    // --- W register residency: wave w owns channels w*16 + lr
    const int w = tid >> 6, l = tid & 63, lr = l & 15, lg = l >> 4;
    bf16x8 wreg[13];
    {
        const __bf16* wb = Wbf + (size_t)(w * 16 + lr) * 416 + lg * 8;
#pragma unroll
        for (int ks = 0; ks < 13; ++ks)
            wreg[ks] = *(const bf16x8*)(wb + ks * 32);
    }
    const int chan = w * 16 + lr;
    const float gam = lng[chan], bet = lnb[chan];

    // --- prologue: all 8 rows' neighbor atoms + indices; zero both sbufs
    if (tid < 256) {
        const int r8 = tid >> 5, e = tid & 31;
        const int j = (int)eidx_f[(size_t)(row0 + r8) * KNB + e];
        jR8[r8][e] = Ridx[b * LEN + j];
        jC8[r8][e] = Chain[b * LEN + j];
        load_res_atoms(Xb + j * 12, &natoms8[r8][e][0]);
    } else if (tid < 264) {
        const int r8 = tid - 256;
        load_res_atoms(Xb + (size_t)(i0 + r8) * 12, &iatoms8[r8][0]);
    } else if (tid >= 384) {
        sbuf[(tid - 384) >> 6][(tid - 384) & 63] = 0.0f;
    }
    __syncthreads();

    // --- features for row 0
    {
        const int r8 = 0;
        const int Ri = Ridx[b * LEN + i0];
        const int Ci = Chain[b * LEN + i0];
        {
            const int e = tid >> 4, p = tid & 15;
            const int drel = jR8[r8][e] - Ri;
            const int same = (jC8[r8][e] == Ci);
            int dc = drel + 32;
            dc = dc < 0 ? 0 : (dc > 64 ? 64 : dc);
            const int df = same ? dc : 65;
            featE[e * FSTRIDE + p] = (__bf16)(W_pos[p * 66 + df] + b_pos[p]);
        }
#pragma unroll
        for (int it = 0; it < 2; ++it) {
            const int task = tid + it * 512;
            if (task < 800) {
                const int mn = task >> 5, e = task & 31;
                const int m = mn / 5, n = mn - m * 5;
                const float ax = iatoms8[r8][m * 3 + 0];
                const float ay = iatoms8[r8][m * 3 + 1];
                const float az = iatoms8[r8][m * 3 + 2];
                const float* na = &natoms8[r8][e][n * 3];
                const float dx = ax - na[0], dy = ay - na[1], dz = az - na[2];
                const float D = sqrtf(dx * dx + dy * dy + dz * dz + 1e-6f);
                bf16x8 v0, v1;
#pragma unroll
                for (int r = 0; r < 8; ++r) {
                    const float mu = (float)(2.0 + (double)r * (20.0 / 15.0));
                    const float t = D - mu;
                    v0[r] = (__bf16)__expf(-(t * t) * (1.0f / 1.5625f));
                }
#pragma unroll
                for (int r = 8; r < 16; ++r) {
                    const float mu = (float)(2.0 + (double)r * (20.0 / 15.0));
                    const float t = D - mu;
                    v1[r - 8] = (__bf16)__expf(-(t * t) * (1.0f / 1.5625f));
                }
                *(bf16x8*)(featE + e * FSTRIDE + 16 + mn * 16)     = v0;
                *(bf16x8*)(featE + e * FSTRIDE + 16 + mn * 16 + 8) = v1;
            }
        }
    }
    __syncthreads();

    for (int r8 = 0; r8 < 8; ++r8) {
        const int row = row0 + r8;
        const int par = r8 & 1;

        // === region B: zero next sbuf, GEMM, per-(wave,edge) partials ===
        if (tid < 64) sbuf[par ^ 1][tid] = 0.0f;

        f32x4 acc0 = {0.f, 0.f, 0.f, 0.f}, acc1 = acc0;
        {
            const __bf16* fb0 = featE + lr * FSTRIDE + lg * 8;
            const __bf16* fb1 = featE + (16 + lr) * FSTRIDE + lg * 8;
#pragma unroll
            for (int ks = 0; ks < 13; ++ks) {
                const bf16x8 a0 = *(const bf16x8*)(fb0 + ks * 32);
                const bf16x8 a1 = *(const bf16x8*)(fb1 + ks * 32);
                acc0 = __builtin_amdgcn_mfma_f32_16x16x32_bf16(a0, wreg[ks], acc0, 0, 0, 0);
                acc1 = __builtin_amdgcn_mfma_f32_16x16x32_bf16(a1, wreg[ks], acc1, 0, 0, 0);
            }
        }
        // reduce across the 16 lr-lanes (channels within wave), accumulate in LDS
#pragma unroll
        for (int rr = 0; rr < 4; ++rr) {
            float s0 = acc0[rr], q0 = acc0[rr] * acc0[rr];
            float s1 = acc1[rr], q1 = acc1[rr] * acc1[rr];
#pragma unroll
            for (int off = 1; off < 16; off <<= 1) {
                s0 += __shfl_xor(s0, off, 64);
                q0 += __shfl_xor(q0, off, 64);
                s1 += __shfl_xor(s1, off, 64);
                q1 += __shfl_xor(q1, off, 64);
            }
            if (lr == 0) {
                const int e0 = lg * 4 + rr;
                atomicAdd(&sbuf[par][e0 * 2 + 0], s0);
                atomicAdd(&sbuf[par][e0 * 2 + 1], q0);
                atomicAdd(&sbuf[par][(16 + e0) * 2 + 0], s1);
                atomicAdd(&sbuf[par][(16 + e0) * 2 + 1], q1);
            }
        }
        __syncthreads();

        // === region C: LN from registers + store; then next row's features ===
        {
            float* orow = outE + (size_t)(row * KNB) * HID + chan;
#pragma unroll
            for (int rr = 0; rr < 4; ++rr) {
                const int e0 = lg * 4 + rr;
                const float sS0 = sbuf[par][e0 * 2 + 0];
                const float sQ0 = sbuf[par][e0 * 2 + 1];
                const float mean0 = sS0 * (1.0f / 128.0f);
                const float rstd0 = rsqrtf(sQ0 * (1.0f / 128.0f) - mean0 * mean0 + 1e-5f);
                orow[(size_t)e0 * HID] = (acc0[rr] - mean0) * rstd0 * gam + bet;

                const float sS1 = sbuf[par][(16 + e0) * 2 + 0];
                const float sQ1 = sbuf[par][(16 + e0) * 2 + 1];
                const float mean1 = sS1 * (1.0f / 128.0f);
                const float rstd1 = rsqrtf(sQ1 * (1.0f / 128.0f) - mean1 * mean1 + 1e-5f);
                orow[(size_t)(16 + e0) * HID] = (acc1[rr] - mean1) * rstd1 * gam + bet;
            }
        }
        if (r8 < 7) {
            const int rn = r8 + 1;
            const int i = i0 + rn;
            const int Ri = Ridx[b * LEN + i];
            const int Ci = Chain[b * LEN + i];
            {
                const int e = tid >> 4, p = tid & 15;
                const int drel = jR8[rn][e] - Ri;
                const int same = (jC8[rn][e] == Ci);
                int dc = drel + 32;
                dc = dc < 0 ? 0 : (dc > 64 ? 64 : dc);
                const int df = same ? dc : 65;
                featE[e * FSTRIDE + p] = (__bf16)(W_pos[p * 66 + df] + b_pos[p]);
            }
#pragma unroll
            for (int it = 0; it < 2; ++it) {
                const int task = tid + it * 512;
                if (task < 800) {
                    const int mn = task >> 5, e = task & 31;
                    const int m = mn / 5, n = mn - m * 5;
                    const float ax = iatoms8[rn][m * 3 + 0];
                    const float ay = iatoms8[rn][m * 3 + 1];
                    const float az = iatoms8[rn][m * 3 + 2];
                    const float* na = &natoms8[rn][e][n * 3];
                    const float dx = ax - na[0], dy = ay - na[1], dz = az - na[2];
                    const float D = sqrtf(dx * dx + dy * dy + dz * dz + 1e-6f);
                    bf16x8 v0, v1;
#pragma unroll
                    for (int r = 0; r < 8; ++r) {
                        const float mu = (float)(2.0 + (double)r * (20.0 / 15.0));
                        const float t = D - mu;
                        v0[r] = (__bf16)__expf(-(t * t) * (1.0f / 1.5625f));
                    }
#pragma unroll
                    for (int r = 8; r < 16; ++r) {
                        const float mu = (float)(2.0 + (double)r * (20.0 / 15.0));
                        const float t = D - mu;
                        v1[r - 8] = (__bf16)__expf(-(t * t) * (1.0f / 1.5625f));
                    }
                    *(bf16x8*)(featE + e * FSTRIDE + 16 + mn * 16)     = v0;
                    *(bf16x8*)(featE + e * FSTRIDE + 16 + mn * 16 + 8) = v1;
                }
            }
        }
        __syncthreads();
    }
}

extern "C" void kernel_launch(void* const* d_in, const int* in_sizes, int n_in,
                              void* d_out, int out_size, void* d_ws, size_t ws_size,
                              hipStream_t stream) {
    const float* X      = (const float*)d_in[0];
    const float* mask   = (const float*)d_in[1];
    const int*   Ridx   = (const int*)d_in[2];
    const int*   Chain  = (const int*)d_in[3];
    const float* W_pos  = (const float*)d_in[4];
    const float* b_pos  = (const float*)d_in[5];
    const float* W_edge = (const float*)d_in[6];
    const float* lng    = (const float*)d_in[7];
    const float* lnb    = (const float*)d_in[8];

    float* out  = (float*)d_out;
    float* eidx = out;                           // B*L*K floats (exact ints)
    float* E    = out + (size_t)2 * LEN * KNB;   // B*L*K*HID floats

    float4* CAm = (float4*)d_ws;                          // 64 KiB
    __bf16* Wbf = (__bf16*)((char*)d_ws + 2 * LEN * 16);  // 104 KiB

    const int nrow = 2 * LEN;
    prep_kernel<<<208, 256, 0, stream>>>(X, mask, W_edge, CAm, Wbf);
    topk_kernel<<<nrow, 256, 0, stream>>>(CAm, eidx);
    edge_kernel<<<nrow / 8, 512, 0, stream>>>(X, Ridx, Chain, W_pos, b_pos, Wbf,
                                              lng, lnb, eidx, E);
}

// Round 6
// 93.373 us; speedup vs baseline: 1.2472x; 1.2472x over previous
//
#include <hip/hip_runtime.h>
#include <hip/hip_bf16.h>

#define LEN   2048
#define KNB   32
#define HID   128

typedef unsigned long long ull;
typedef unsigned int uint32;
typedef __bf16 bf16x8 __attribute__((ext_vector_type(8)));
typedef float  f32x4  __attribute__((ext_vector_type(4)));

// ---------------------------------------------------------------------------
// Kernel 0: prep — pack CA coords + mask penalty as float4, convert W to bf16.
// ---------------------------------------------------------------------------
__global__ __launch_bounds__(256) void prep_kernel(
    const float* __restrict__ X, const float* __restrict__ mask,
    const float* __restrict__ W_edge,
    float4* __restrict__ CAm, __bf16* __restrict__ Wbf) {
    const int t = blockIdx.x * 256 + threadIdx.x;
    if (t < 2 * LEN) {
        const float* p = X + (size_t)t * 12;
        CAm[t] = make_float4(p[3], p[4], p[5],
                             __fmul_rn(__fsub_rn(1.0f, mask[t]), 1000000.0f));
    }
    Wbf[t] = (__bf16)W_edge[t];
}

// ---------------------------------------------------------------------------
// Kernel 1: exact top-K=32 via histogram-select (unchanged — working).
// ---------------------------------------------------------------------------
__global__ __launch_bounds__(256) void topk_kernel(
    const float4* __restrict__ CAm, float* __restrict__ eidx_out) {
    const int row = blockIdx.x;
    const int b = row >> 11;
    const int i = row & (LEN - 1);
    const int tid = threadIdx.x;

    __shared__ int hist[512];
    __shared__ ull cand[LEN];
    __shared__ int candcnt;
    __shared__ int selB;

    const float4* C = CAm + (size_t)b * LEN;
    const float4 ci = C[i];

    uint32 d2b[8];
#pragma unroll
    for (int q = 0; q < 8; ++q) {
        const float4 cj = C[q * 256 + tid];
        float dx = __fsub_rn(ci.x, cj.x);
        float dy = __fsub_rn(ci.y, cj.y);
        float dz = __fsub_rn(ci.z, cj.z);
        float d2 = __fadd_rn(__fadd_rn(__fmul_rn(dx, dx), __fmul_rn(dy, dy)),
                             __fmul_rn(dz, dz));
        d2 = __fadd_rn(d2, cj.w);
        d2b[q] = __float_as_uint(d2);
    }

    hist[tid] = 0; hist[tid + 256] = 0;
    if (tid == 0) candcnt = 0;
    __syncthreads();
#pragma unroll
    for (int q = 0; q < 8; ++q) atomicAdd(&hist[d2b[q] >> 22], 1);
    __syncthreads();

    if (tid < 64) {
        int loc[8];
        int s = 0;
#pragma unroll
        for (int t = 0; t < 8; ++t) { loc[t] = hist[tid * 8 + t]; s += loc[t]; }
        int incl = s;
#pragma unroll
        for (int off = 1; off < 64; off <<= 1) {
            int o = __shfl_up(incl, off, 64);
            if (tid >= off) incl += o;
        }
        const int excl = incl - s;
        if (excl < KNB && incl >= KNB) {
            int c = excl;
#pragma unroll
            for (int t = 0; t < 8; ++t) {
                int c2 = c + loc[t];
                if (c < KNB && c2 >= KNB) selB = tid * 8 + t;
                c = c2;
            }
        }
    }
    __syncthreads();
    const uint32 B = (uint32)selB;

#pragma unroll
    for (int q = 0; q < 8; ++q) {
        if ((d2b[q] >> 22) <= B) {
            int p = atomicAdd(&candcnt, 1);
            cand[p] = (((ull)d2b[q]) << 32) | (uint32)(q * 256 + tid);
        }
    }
    __syncthreads();
    const int M = candcnt;

    for (int c = tid; c < M; c += 256) {
        const ull k = cand[c];
        int r = 0;
        for (int m = 0; m < M; ++m) r += (cand[m] < k);
        if (r < KNB)
            eidx_out[(size_t)row * KNB + r] = (float)(uint32)(k & 0xFFFFFFFFull);
    }
}

// ---------------------------------------------------------------------------
// Kernel 2: 8 rows/block, 512 thr (8 waves). Wave w: W-slice (16 ch x K=416)
// register-resident (launch_bounds(512,4): budget 128 — proven resident in
// R4; (512,6) caused rematerialize-by-reload, FETCH 124MB, 2.4x regression).
// Per row: [GEMM | shfl-reduce | per-wave LDS slots] barrier [LN from regs +
// store | next row's features] barrier. No atomics, no hbuf.
// ---------------------------------------------------------------------------
__device__ __forceinline__ void load_res_atoms(const float* __restrict__ p, float* dst) {
    const float Nx = p[0], Ny = p[1], Nz = p[2];
    const float Ax = p[3], Ay = p[4], Az = p[5];
    const float Cx = p[6], Cy = p[7], Cz = p[8];
    const float Ox = p[9], Oy = p[10], Oz = p[11];
    const float bx = Ax - Nx, by = Ay - Ny, bz = Az - Nz;
    const float cx = Cx - Ax, cy = Cy - Ay, cz = Cz - Az;
    const float axv = by * cz - bz * cy;
    const float ayv = bz * cx - bx * cz;
    const float azv = bx * cy - by * cx;
    dst[0] = Nx;  dst[1] = Ny;  dst[2] = Nz;
    dst[3] = Ax;  dst[4] = Ay;  dst[5] = Az;
    dst[6] = Cx;  dst[7] = Cy;  dst[8] = Cz;
    dst[9] = Ox;  dst[10] = Oy; dst[11] = Oz;
    dst[12] = -0.58273431f * axv + 0.56802827f * bx + -0.54067466f * cx + Ax;
    dst[13] = -0.58273431f * ayv + 0.56802827f * by + -0.54067466f * cy + Ay;
    dst[14] = -0.58273431f * azv + 0.56802827f * bz + -0.54067466f * cz + Az;
}

#define FSTRIDE 424   // bf16; dw-stride 212 % 32 = 20 -> only 2-way aliasing

__global__ __launch_bounds__(512, 4) void edge_kernel(
    const float* __restrict__ X,
    const int* __restrict__ Ridx, const int* __restrict__ Chain,
    const float* __restrict__ W_pos, const float* __restrict__ b_pos,
    const __bf16* __restrict__ Wbf,
    const float* __restrict__ lng, const float* __restrict__ lnb,
    const float* __restrict__ eidx_f, float* __restrict__ outE) {
    const int tid = threadIdx.x;
    const int row0 = blockIdx.x * 8;
    const int b = row0 >> 11;                 // 2048 % 8 == 0: no batch straddle
    const int i0 = row0 & (LEN - 1);

    __shared__ __align__(16) __bf16 featE[32 * FSTRIDE];  // 27136 B
    __shared__ float natoms8[8][32][17];                  // 17408 B
    __shared__ float iatoms8[8][16];                      //   512 B
    __shared__ int jR8[8][32], jC8[8][32];                //  2048 B
    __shared__ float pS[32][8], pQ[32][8];                //  2048 B: [edge][wave]

    const float* Xb = X + (size_t)b * LEN * 12;

    // --- W register residency: wave w owns channels w*16 + lr
    const int w = tid >> 6, l = tid & 63, lr = l & 15, lg = l >> 4;
    bf16x8 wreg[13];
    {
        const __bf16* wb = Wbf + (size_t)(w * 16 + lr) * 416 + lg * 8;
#pragma unroll
        for (int ks = 0; ks < 13; ++ks)
            wreg[ks] = *(const bf16x8*)(wb + ks * 32);
    }
    const int chan = w * 16 + lr;
    const float gam = lng[chan], bet = lnb[chan];

    // --- prologue: all 8 rows' neighbor atoms + indices
    if (tid < 256) {
        const int r8 = tid >> 5, e = tid & 31;
        const int j = (int)eidx_f[(size_t)(row0 + r8) * KNB + e];
        jR8[r8][e] = Ridx[b * LEN + j];
        jC8[r8][e] = Chain[b * LEN + j];
        load_res_atoms(Xb + j * 12, &natoms8[r8][e][0]);
    } else if (tid < 264) {
        const int r8 = tid - 256;
        load_res_atoms(Xb + (size_t)(i0 + r8) * 12, &iatoms8[r8][0]);
    }
    __syncthreads();

    // --- features for row 0
    {
        const int r8 = 0;
        const int Ri = Ridx[b * LEN + i0];
        const int Ci = Chain[b * LEN + i0];
        {
            const int e = tid >> 4, p = tid & 15;
            const int drel = jR8[r8][e] - Ri;
            const int same = (jC8[r8][e] == Ci);
            int dc = drel + 32;
            dc = dc < 0 ? 0 : (dc > 64 ? 64 : dc);
            const int df = same ? dc : 65;
            featE[e * FSTRIDE + p] = (__bf16)(W_pos[p * 66 + df] + b_pos[p]);
        }
#pragma unroll
        for (int it = 0; it < 2; ++it) {
            const int task = tid + it * 512;
            if (task < 800) {
                const int mn = task >> 5, e = task & 31;
                const int m = mn / 5, n = mn - m * 5;
                const float ax = iatoms8[r8][m * 3 + 0];
                const float ay = iatoms8[r8][m * 3 + 1];
                const float az = iatoms8[r8][m * 3 + 2];
                const float* na = &natoms8[r8][e][n * 3];
                const float dx = ax - na[0], dy = ay - na[1], dz = az - na[2];
                const float D = sqrtf(dx * dx + dy * dy + dz * dz + 1e-6f);
                bf16x8 v0, v1;
#pragma unroll
                for (int r = 0; r < 8; ++r) {
                    const float mu = (float)(2.0 + (double)r * (20.0 / 15.0));
                    const float t = D - mu;
                    v0[r] = (__bf16)__expf(-(t * t) * (1.0f / 1.5625f));
                }
#pragma unroll
                for (int r = 8; r < 16; ++r) {
                    const float mu = (float)(2.0 + (double)r * (20.0 / 15.0));
                    const float t = D - mu;
                    v1[r - 8] = (__bf16)__expf(-(t * t) * (1.0f / 1.5625f));
                }
                *(bf16x8*)(featE + e * FSTRIDE + 16 + mn * 16)     = v0;
                *(bf16x8*)(featE + e * FSTRIDE + 16 + mn * 16 + 8) = v1;
            }
        }
    }
    __syncthreads();

    for (int r8 = 0; r8 < 8; ++r8) {
        const int row = row0 + r8;

        // === region B: GEMM + per-(wave,edge) partial sums into own slots ===
        f32x4 acc0 = {0.f, 0.f, 0.f, 0.f}, acc1 = acc0;
        {
            const __bf16* fb0 = featE + lr * FSTRIDE + lg * 8;
            const __bf16* fb1 = featE + (16 + lr) * FSTRIDE + lg * 8;
#pragma unroll
            for (int ks = 0; ks < 13; ++ks) {
                const bf16x8 a0 = *(const bf16x8*)(fb0 + ks * 32);
                const bf16x8 a1 = *(const bf16x8*)(fb1 + ks * 32);
                acc0 = __builtin_amdgcn_mfma_f32_16x16x32_bf16(a0, wreg[ks], acc0, 0, 0, 0);
                acc1 = __builtin_amdgcn_mfma_f32_16x16x32_bf16(a1, wreg[ks], acc1, 0, 0, 0);
            }
        }
#pragma unroll
        for (int rr = 0; rr < 4; ++rr) {
            float s0 = acc0[rr], q0 = acc0[rr] * acc0[rr];
            float s1 = acc1[rr], q1 = acc1[rr] * acc1[rr];
#pragma unroll
            for (int off = 1; off < 16; off <<= 1) {
                s0 += __shfl_xor(s0, off, 64);
                q0 += __shfl_xor(q0, off, 64);
                s1 += __shfl_xor(s1, off, 64);
                q1 += __shfl_xor(q1, off, 64);
            }
            if (lr == 0) {
                const int e0 = lg * 4 + rr;
                pS[e0][w] = s0;      pQ[e0][w] = q0;
                pS[16 + e0][w] = s1; pQ[16 + e0][w] = q1;
            }
        }
        __syncthreads();

        // === region C: LN from registers + store; then next row's features ===
        {
            float* orow = outE + (size_t)(row * KNB) * HID + chan;
#pragma unroll
            for (int rr = 0; rr < 4; ++rr) {
                const int e0 = lg * 4 + rr;
                float sS0 = 0.f, sQ0 = 0.f, sS1 = 0.f, sQ1 = 0.f;
#pragma unroll
                for (int ww = 0; ww < 8; ++ww) {
                    sS0 += pS[e0][ww];      sQ0 += pQ[e0][ww];
                    sS1 += pS[16 + e0][ww]; sQ1 += pQ[16 + e0][ww];
                }
                const float mean0 = sS0 * (1.0f / 128.0f);
                const float rstd0 = rsqrtf(sQ0 * (1.0f / 128.0f) - mean0 * mean0 + 1e-5f);
                orow[(size_t)e0 * HID] = (acc0[rr] - mean0) * rstd0 * gam + bet;

                const float mean1 = sS1 * (1.0f / 128.0f);
                const float rstd1 = rsqrtf(sQ1 * (1.0f / 128.0f) - mean1 * mean1 + 1e-5f);
                orow[(size_t)(16 + e0) * HID] = (acc1[rr] - mean1) * rstd1 * gam + bet;
            }
        }
        if (r8 < 7) {
            const int rn = r8 + 1;
            const int i = i0 + rn;
            const int Ri = Ridx[b * LEN + i];
            const int Ci = Chain[b * LEN + i];
            {
                const int e = tid >> 4, p = tid & 15;
                const int drel = jR8[rn][e] - Ri;
                const int same = (jC8[rn][e] == Ci);
                int dc = drel + 32;
                dc = dc < 0 ? 0 : (dc > 64 ? 64 : dc);
                const int df = same ? dc : 65;
                featE[e * FSTRIDE + p] = (__bf16)(W_pos[p * 66 + df] + b_pos[p]);
            }
#pragma unroll
            for (int it = 0; it < 2; ++it) {
                const int task = tid + it * 512;
                if (task < 800) {
                    const int mn = task >> 5, e = task & 31;
                    const int m = mn / 5, n = mn - m * 5;
                    const float ax = iatoms8[rn][m * 3 + 0];
                    const float ay = iatoms8[rn][m * 3 + 1];
                    const float az = iatoms8[rn][m * 3 + 2];
                    const float* na = &natoms8[rn][e][n * 3];
                    const float dx = ax - na[0], dy = ay - na[1], dz = az - na[2];
                    const float D = sqrtf(dx * dx + dy * dy + dz * dz + 1e-6f);
                    bf16x8 v0, v1;
#pragma unroll
                    for (int r = 0; r < 8; ++r) {
                        const float mu = (float)(2.0 + (double)r * (20.0 / 15.0));
                        const float t = D - mu;
                        v0[r] = (__bf16)__expf(-(t * t) * (1.0f / 1.5625f));
                    }
#pragma unroll
                    for (int r = 8; r < 16; ++r) {
                        const float mu = (float)(2.0 + (double)r * (20.0 / 15.0));
                        const float t = D - mu;
                        v1[r - 8] = (__bf16)__expf(-(t * t) * (1.0f / 1.5625f));
                    }
                    *(bf16x8*)(featE + e * FSTRIDE + 16 + mn * 16)     = v0;
                    *(bf16x8*)(featE + e * FSTRIDE + 16 + mn * 16 + 8) = v1;
                }
            }
        }
        __syncthreads();
    }
}

extern "C" void kernel_launch(void* const* d_in, const int* in_sizes, int n_in,
                              void* d_out, int out_size, void* d_ws, size_t ws_size,
                              hipStream_t stream) {
    const float* X      = (const float*)d_in[0];
    const float* mask   = (const float*)d_in[1];
    const int*   Ridx   = (const int*)d_in[2];
    const int*   Chain  = (const int*)d_in[3];
    const float* W_pos  = (const float*)d_in[4];
    const float* b_pos  = (const float*)d_in[5];
    const float* W_edge = (const float*)d_in[6];
    const float* lng    = (const float*)d_in[7];
    const float* lnb    = (const float*)d_in[8];

    float* out  = (float*)d_out;
    float* eidx = out;                           // B*L*K floats (exact ints)
    float* E    = out + (size_t)2 * LEN * KNB;   // B*L*K*HID floats

    float4* CAm = (float4*)d_ws;                          // 64 KiB
    __bf16* Wbf = (__bf16*)((char*)d_ws + 2 * LEN * 16);  // 104 KiB

    const int nrow = 2 * LEN;
    prep_kernel<<<208, 256, 0, stream>>>(X, mask, W_edge, CAm, Wbf);
    topk_kernel<<<nrow, 256, 0, stream>>>(CAm, eidx);
    edge_kernel<<<nrow / 8, 512, 0, stream>>>(X, Ridx, Chain, W_pos, b_pos, Wbf,
                                              lng, lnb, eidx, E);
}

// Round 7
// 71.696 us; speedup vs baseline: 1.6243x; 1.3024x over previous
//
#include <hip/hip_runtime.h>
#include <hip/hip_bf16.h>

#define LEN   2048
#define KNB   32
#define HID   128

typedef unsigned long long ull;
typedef unsigned int uint32;
typedef __bf16 bf16x8 __attribute__((ext_vector_type(8)));
typedef float  f32x4  __attribute__((ext_vector_type(4)));

// ---------------------------------------------------------------------------
// Kernel 0: prep — pack CA coords + mask penalty as float4, convert W to bf16.
// ---------------------------------------------------------------------------
__global__ __launch_bounds__(256) void prep_kernel(
    const float* __restrict__ X, const float* __restrict__ mask,
    const float* __restrict__ W_edge,
    float4* __restrict__ CAm, __bf16* __restrict__ Wbf) {
    const int t = blockIdx.x * 256 + threadIdx.x;
    if (t < 2 * LEN) {
        const float* p = X + (size_t)t * 12;
        CAm[t] = make_float4(p[3], p[4], p[5],
                             __fmul_rn(__fsub_rn(1.0f, mask[t]), 1000000.0f));
    }
    Wbf[t] = (__bf16)W_edge[t];
}

// ---------------------------------------------------------------------------
// Kernel 1: exact top-K=32 via histogram-select (unchanged — working, ~10us).
// ---------------------------------------------------------------------------
__global__ __launch_bounds__(256) void topk_kernel(
    const float4* __restrict__ CAm, float* __restrict__ eidx_out) {
    const int row = blockIdx.x;
    const int b = row >> 11;
    const int i = row & (LEN - 1);
    const int tid = threadIdx.x;

    __shared__ int hist[512];
    __shared__ ull cand[LEN];
    __shared__ int candcnt;
    __shared__ int selB;

    const float4* C = CAm + (size_t)b * LEN;
    const float4 ci = C[i];

    uint32 d2b[8];
#pragma unroll
    for (int q = 0; q < 8; ++q) {
        const float4 cj = C[q * 256 + tid];
        float dx = __fsub_rn(ci.x, cj.x);
        float dy = __fsub_rn(ci.y, cj.y);
        float dz = __fsub_rn(ci.z, cj.z);
        float d2 = __fadd_rn(__fadd_rn(__fmul_rn(dx, dx), __fmul_rn(dy, dy)),
                             __fmul_rn(dz, dz));
        d2 = __fadd_rn(d2, cj.w);
        d2b[q] = __float_as_uint(d2);
    }

    hist[tid] = 0; hist[tid + 256] = 0;
    if (tid == 0) candcnt = 0;
    __syncthreads();
#pragma unroll
    for (int q = 0; q < 8; ++q) atomicAdd(&hist[d2b[q] >> 22], 1);
    __syncthreads();

    if (tid < 64) {
        int loc[8];
        int s = 0;
#pragma unroll
        for (int t = 0; t < 8; ++t) { loc[t] = hist[tid * 8 + t]; s += loc[t]; }
        int incl = s;
#pragma unroll
        for (int off = 1; off < 64; off <<= 1) {
            int o = __shfl_up(incl, off, 64);
            if (tid >= off) incl += o;
        }
        const int excl = incl - s;
        if (excl < KNB && incl >= KNB) {
            int c = excl;
#pragma unroll
            for (int t = 0; t < 8; ++t) {
                int c2 = c + loc[t];
                if (c < KNB && c2 >= KNB) selB = tid * 8 + t;
                c = c2;
            }
        }
    }
    __syncthreads();
    const uint32 B = (uint32)selB;

#pragma unroll
    for (int q = 0; q < 8; ++q) {
        if ((d2b[q] >> 22) <= B) {
            int p = atomicAdd(&candcnt, 1);
            cand[p] = (((ull)d2b[q]) << 32) | (uint32)(q * 256 + tid);
        }
    }
    __syncthreads();
    const int M = candcnt;

    for (int c = tid; c < M; c += 256) {
        const ull k = cand[c];
        int r = 0;
        for (int m = 0; m < M; ++m) r += (cand[m] < k);
        if (r < KNB)
            eidx_out[(size_t)row * KNB + r] = (float)(uint32)(k & 0xFFFFFFFFull);
    }
}

// ---------------------------------------------------------------------------
// Kernel 2: 4 rows/block, 512 thr (8 waves), 1024 blocks -> 3 blocks/CU
// (LDS 48.8 KB). Wave w: W-slice (16 ch x K=416) register-resident
// (launch_bounds(512,4) — (512,6) caused W rematerialization, see R5).
// Row pipeline: [GEMM(r) + load atoms(r+1) + scatter->hbuf] bar
//               [LN(r) from hbuf + store | features(r+1)] bar.
// ---------------------------------------------------------------------------
__device__ __forceinline__ void load_res_atoms(const float* __restrict__ p, float* dst) {
    const float Nx = p[0], Ny = p[1], Nz = p[2];
    const float Ax = p[3], Ay = p[4], Az = p[5];
    const float Cx = p[6], Cy = p[7], Cz = p[8];
    const float Ox = p[9], Oy = p[10], Oz = p[11];
    const float bx = Ax - Nx, by = Ay - Ny, bz = Az - Nz;
    const float cx = Cx - Ax, cy = Cy - Ay, cz = Cz - Az;
    const float axv = by * cz - bz * cy;
    const float ayv = bz * cx - bx * cz;
    const float azv = bx * cy - by * cx;
    dst[0] = Nx;  dst[1] = Ny;  dst[2] = Nz;
    dst[3] = Ax;  dst[4] = Ay;  dst[5] = Az;
    dst[6] = Cx;  dst[7] = Cy;  dst[8] = Cz;
    dst[9] = Ox;  dst[10] = Oy; dst[11] = Oz;
    dst[12] = -0.58273431f * axv + 0.56802827f * bx + -0.54067466f * cx + Ax;
    dst[13] = -0.58273431f * ayv + 0.56802827f * by + -0.54067466f * cy + Ay;
    dst[14] = -0.58273431f * azv + 0.56802827f * bz + -0.54067466f * cz + Az;
}

#define FSTRIDE 424   // bf16; dw-stride 212 % 32 = 20 -> only 2-way aliasing

__device__ __forceinline__ void compute_features(
    int tid, int Ri, int Ci,
    const float* __restrict__ W_pos, const float* __restrict__ b_pos,
    const int* jR, const int* jC,
    const float (*natoms)[17], const float* iatoms,
    __bf16* featE) {
    {
        const int e = tid >> 4, p = tid & 15;
        const int drel = jR[e] - Ri;
        const int same = (jC[e] == Ci);
        int dc = drel + 32;
        dc = dc < 0 ? 0 : (dc > 64 ? 64 : dc);
        const int df = same ? dc : 65;
        featE[e * FSTRIDE + p] = (__bf16)(W_pos[p * 66 + df] + b_pos[p]);
    }
#pragma unroll
    for (int it = 0; it < 2; ++it) {
        const int task = tid + it * 512;
        if (task < 800) {
            const int mn = task >> 5, e = task & 31;
            const int m = mn / 5, n = mn - m * 5;
            const float ax = iatoms[m * 3 + 0];
            const float ay = iatoms[m * 3 + 1];
            const float az = iatoms[m * 3 + 2];
            const float* na = &natoms[e][n * 3];
            const float dx = ax - na[0], dy = ay - na[1], dz = az - na[2];
            const float D = sqrtf(dx * dx + dy * dy + dz * dz + 1e-6f);
            bf16x8 v0, v1;
#pragma unroll
            for (int r = 0; r < 8; ++r) {
                const float mu = (float)(2.0 + (double)r * (20.0 / 15.0));
                const float t = D - mu;
                v0[r] = (__bf16)__expf(-(t * t) * (1.0f / 1.5625f));
            }
#pragma unroll
            for (int r = 8; r < 16; ++r) {
                const float mu = (float)(2.0 + (double)r * (20.0 / 15.0));
                const float t = D - mu;
                v1[r - 8] = (__bf16)__expf(-(t * t) * (1.0f / 1.5625f));
            }
            *(bf16x8*)(featE + e * FSTRIDE + 16 + mn * 16)     = v0;
            *(bf16x8*)(featE + e * FSTRIDE + 16 + mn * 16 + 8) = v1;
        }
    }
}

__global__ __launch_bounds__(512, 4) void edge_kernel(
    const float* __restrict__ X,
    const int* __restrict__ Ridx, const int* __restrict__ Chain,
    const float* __restrict__ W_pos, const float* __restrict__ b_pos,
    const __bf16* __restrict__ Wbf,
    const float* __restrict__ lng, const float* __restrict__ lnb,
    const float* __restrict__ eidx_f, float* __restrict__ outE) {
    const int tid = threadIdx.x;
    const int row0 = blockIdx.x * 4;
    const int b = row0 >> 11;                 // 2048 % 4 == 0: no batch straddle
    const int i0 = row0 & (LEN - 1);

    __shared__ __align__(16) __bf16 featE[32 * FSTRIDE];  // 27136 B
    __shared__ __align__(16) float hbuf[32 * 132];        // 16896 B
    __shared__ float natoms[2][32][17];                   //  4352 B
    __shared__ float iatoms[2][16];                       //   128 B
    __shared__ int jR[2][32], jC[2][32];                  //   512 B

    const float* Xb = X + (size_t)b * LEN * 12;

    // --- W register residency: wave w owns channels w*16 + lr
    const int w = tid >> 6, l = tid & 63, lr = l & 15, lg = l >> 4;
    bf16x8 wreg[13];
    {
        const __bf16* wb = Wbf + (size_t)(w * 16 + lr) * 416 + lg * 8;
#pragma unroll
        for (int ks = 0; ks < 13; ++ks)
            wreg[ks] = *(const bf16x8*)(wb + ks * 32);
    }

    // --- prologue: row 0 atoms + features
    if (tid < 32) {
        const int j = (int)eidx_f[(size_t)row0 * KNB + tid];
        jR[0][tid] = Ridx[b * LEN + j];
        jC[0][tid] = Chain[b * LEN + j];
        load_res_atoms(Xb + j * 12, &natoms[0][tid][0]);
    } else if (tid == 32) {
        load_res_atoms(Xb + (size_t)i0 * 12, &iatoms[0][0]);
    }
    __syncthreads();
    compute_features(tid, Ridx[b * LEN + i0], Chain[b * LEN + i0],
                     W_pos, b_pos, jR[0], jC[0], natoms[0], iatoms[0], featE);
    __syncthreads();

    for (int r = 0; r < 4; ++r) {
        const int row = row0 + r;
        const int nb = (r + 1) & 1;

        // === region B: GEMM(r); load row r+1 atoms; scatter acc -> hbuf ===
        f32x4 acc0 = {0.f, 0.f, 0.f, 0.f}, acc1 = acc0;
        {
            const __bf16* fb0 = featE + lr * FSTRIDE + lg * 8;
            const __bf16* fb1 = featE + (16 + lr) * FSTRIDE + lg * 8;
#pragma unroll
            for (int ks = 0; ks < 13; ++ks) {
                const bf16x8 a0 = *(const bf16x8*)(fb0 + ks * 32);
                const bf16x8 a1 = *(const bf16x8*)(fb1 + ks * 32);
                acc0 = __builtin_amdgcn_mfma_f32_16x16x32_bf16(a0, wreg[ks], acc0, 0, 0, 0);
                acc1 = __builtin_amdgcn_mfma_f32_16x16x32_bf16(a1, wreg[ks], acc1, 0, 0, 0);
            }
        }
        if (r < 3) {
            if (tid < 32) {
                const int j = (int)eidx_f[(size_t)(row + 1) * KNB + tid];
                jR[nb][tid] = Ridx[b * LEN + j];
                jC[nb][tid] = Chain[b * LEN + j];
                load_res_atoms(Xb + j * 12, &natoms[nb][tid][0]);
            } else if (tid == 32) {
                load_res_atoms(Xb + (size_t)(i0 + r + 1) * 12, &iatoms[nb][0]);
            }
        }
        // scatter (2-way bank aliasing only — free)
#pragma unroll
        for (int rr = 0; rr < 4; ++rr) {
            hbuf[(lg * 4 + rr) * 132 + w * 16 + lr]      = acc0[rr];
            hbuf[(16 + lg * 4 + rr) * 132 + w * 16 + lr] = acc1[rr];
        }
        __syncthreads();

        // === region C: LN(r) from hbuf + store; features(r+1) ===
        {
            const int g = tid >> 4, l2 = tid & 15;
            const float4* hb4 = (const float4*)(hbuf + g * 132 + l2 * 8);
            const float4 v0 = hb4[0], v1 = hb4[1];
            float s = v0.x + v0.y + v0.z + v0.w + v1.x + v1.y + v1.z + v1.w;
            float ssq = v0.x * v0.x + v0.y * v0.y + v0.z * v0.z + v0.w * v0.w
                      + v1.x * v1.x + v1.y * v1.y + v1.z * v1.z + v1.w * v1.w;
#pragma unroll
            for (int off = 1; off < 16; off <<= 1) {
                s += __shfl_xor(s, off, 64);
                ssq += __shfl_xor(ssq, off, 64);
            }
            const float mean = s * (1.0f / 128.0f);
            const float rstd = rsqrtf(ssq * (1.0f / 128.0f) - mean * mean + 1e-5f);

            float4* ob = (float4*)(outE + ((size_t)row * KNB + g) * HID + l2 * 8);
            const float4 g0 = *(const float4*)(lng + l2 * 8);
            const float4 g1 = *(const float4*)(lng + l2 * 8 + 4);
            const float4 b0 = *(const float4*)(lnb + l2 * 8);
            const float4 b1 = *(const float4*)(lnb + l2 * 8 + 4);
            float4 o0, o1;
            o0.x = (v0.x - mean) * rstd * g0.x + b0.x;
            o0.y = (v0.y - mean) * rstd * g0.y + b0.y;
            o0.z = (v0.z - mean) * rstd * g0.z + b0.z;
            o0.w = (v0.w - mean) * rstd * g0.w + b0.w;
            o1.x = (v1.x - mean) * rstd * g1.x + b1.x;
            o1.y = (v1.y - mean) * rstd * g1.y + b1.y;
            o1.z = (v1.z - mean) * rstd * g1.z + b1.z;
            o1.w = (v1.w - mean) * rstd * g1.w + b1.w;
            ob[0] = o0;
            ob[1] = o1;
        }
        if (r < 3) {
            const int i = i0 + r + 1;
            compute_features(tid, Ridx[b * LEN + i], Chain[b * LEN + i],
                             W_pos, b_pos, jR[nb], jC[nb], natoms[nb], iatoms[nb],
                             featE);
        }
        __syncthreads();
    }
}

extern "C" void kernel_launch(void* const* d_in, const int* in_sizes, int n_in,
                              void* d_out, int out_size, void* d_ws, size_t ws_size,
                              hipStream_t stream) {
    const float* X      = (const float*)d_in[0];
    const float* mask   = (const float*)d_in[1];
    const int*   Ridx   = (const int*)d_in[2];
    const int*   Chain  = (const int*)d_in[3];
    const float* W_pos  = (const float*)d_in[4];
    const float* b_pos  = (const float*)d_in[5];
    const float* W_edge = (const float*)d_in[6];
    const float* lng    = (const float*)d_in[7];
    const float* lnb    = (const float*)d_in[8];

    float* out  = (float*)d_out;
    float* eidx = out;                           // B*L*K floats (exact ints)
    float* E    = out + (size_t)2 * LEN * KNB;   // B*L*K*HID floats

    float4* CAm = (float4*)d_ws;                          // 64 KiB
    __bf16* Wbf = (__bf16*)((char*)d_ws + 2 * LEN * 16);  // 104 KiB

    const int nrow = 2 * LEN;
    prep_kernel<<<208, 256, 0, stream>>>(X, mask, W_edge, CAm, Wbf);
    topk_kernel<<<nrow, 256, 0, stream>>>(CAm, eidx);
    edge_kernel<<<nrow / 4, 512, 0, stream>>>(X, Ridx, Chain, W_pos, b_pos, Wbf,
                                              lng, lnb, eidx, E);
}

// Round 8
// 61.113 us; speedup vs baseline: 1.9056x; 1.1732x over previous
//
#include <hip/hip_runtime.h>
#include <hip/hip_bf16.h>

#define LEN   2048
#define KNB   32
#define HID   128

typedef unsigned long long ull;
typedef unsigned int uint32;
typedef float f32x4 __attribute__((ext_vector_type(4)));

// ---------------------------------------------------------------------------
// Kernel 0: prep — pack CA+mask as float4; convert W_edge f32 -> fp8 e4m3.
// 52 blocks x 256 = 13312 threads (= 53248/4 packed W ints).
// ---------------------------------------------------------------------------
__global__ __launch_bounds__(256) void prep_kernel(
    const float* __restrict__ X, const float* __restrict__ mask,
    const float* __restrict__ W_edge,
    float4* __restrict__ CAm, int* __restrict__ Wf8) {
    const int t = blockIdx.x * 256 + threadIdx.x;
    if (t < 2 * LEN) {
        const float* p = X + (size_t)t * 12;
        CAm[t] = make_float4(p[3], p[4], p[5],
                             __fmul_rn(__fsub_rn(1.0f, mask[t]), 1000000.0f));
    }
    if (t < 13312) {
        const float4 w = ((const float4*)W_edge)[t];
        int r = __builtin_amdgcn_cvt_pk_fp8_f32(w.x, w.y, 0, false);
        r = __builtin_amdgcn_cvt_pk_fp8_f32(w.z, w.w, r, true);
        Wf8[t] = r;
    }
}

// ---------------------------------------------------------------------------
// Kernel 1: exact top-K=32 via histogram-select (unchanged — working, ~10us).
// ---------------------------------------------------------------------------
__global__ __launch_bounds__(256) void topk_kernel(
    const float4* __restrict__ CAm, float* __restrict__ eidx_out) {
    const int row = blockIdx.x;
    const int b = row >> 11;
    const int i = row & (LEN - 1);
    const int tid = threadIdx.x;

    __shared__ int hist[512];
    __shared__ ull cand[LEN];
    __shared__ int candcnt;
    __shared__ int selB;

    const float4* C = CAm + (size_t)b * LEN;
    const float4 ci = C[i];

    uint32 d2b[8];
#pragma unroll
    for (int q = 0; q < 8; ++q) {
        const float4 cj = C[q * 256 + tid];
        float dx = __fsub_rn(ci.x, cj.x);
        float dy = __fsub_rn(ci.y, cj.y);
        float dz = __fsub_rn(ci.z, cj.z);
        float d2 = __fadd_rn(__fadd_rn(__fmul_rn(dx, dx), __fmul_rn(dy, dy)),
                             __fmul_rn(dz, dz));
        d2 = __fadd_rn(d2, cj.w);
        d2b[q] = __float_as_uint(d2);
    }

    hist[tid] = 0; hist[tid + 256] = 0;
    if (tid == 0) candcnt = 0;
    __syncthreads();
#pragma unroll
    for (int q = 0; q < 8; ++q) atomicAdd(&hist[d2b[q] >> 22], 1);
    __syncthreads();

    if (tid < 64) {
        int loc[8];
        int s = 0;
#pragma unroll
        for (int t = 0; t < 8; ++t) { loc[t] = hist[tid * 8 + t]; s += loc[t]; }
        int incl = s;
#pragma unroll
        for (int off = 1; off < 64; off <<= 1) {
            int o = __shfl_up(incl, off, 64);
            if (tid >= off) incl += o;
        }
        const int excl = incl - s;
        if (excl < KNB && incl >= KNB) {
            int c = excl;
#pragma unroll
            for (int t = 0; t < 8; ++t) {
                int c2 = c + loc[t];
                if (c < KNB && c2 >= KNB) selB = tid * 8 + t;
                c = c2;
            }
        }
    }
    __syncthreads();
    const uint32 B = (uint32)selB;

#pragma unroll
    for (int q = 0; q < 8; ++q) {
        if ((d2b[q] >> 22) <= B) {
            int p = atomicAdd(&candcnt, 1);
            cand[p] = (((ull)d2b[q]) << 32) | (uint32)(q * 256 + tid);
        }
    }
    __syncthreads();
    const int M = candcnt;

    for (int c = tid; c < M; c += 256) {
        const ull k = cand[c];
        int r = 0;
        for (int m = 0; m < M; ++m) r += (cand[m] < k);
        if (r < KNB)
            eidx_out[(size_t)row * KNB + r] = (float)(uint32)(k & 0xFFFFFFFFull);
    }
}

// ---------------------------------------------------------------------------
// Kernel 2: 4 rows/block, 512 thr (8 waves), 1024 blocks. fp8 GEMM:
// features + W both fp8-e4m3 -> wreg 26 regs (was 52 bf16) -> total ~70 regs
// under launch_bounds(512,6) cap 85 -> 6 waves/SIMD -> 3 blocks/CU.
// All 4 rows' gathers hoisted to one prologue (R4 lesson: in-loop gather
// chains cost ~1us/row). LDS ~39.7KB.
// ---------------------------------------------------------------------------
__device__ __forceinline__ void load_res_atoms(const float* __restrict__ p, float* dst) {
    const float Nx = p[0], Ny = p[1], Nz = p[2];
    const float Ax = p[3], Ay = p[4], Az = p[5];
    const float Cx = p[6], Cy = p[7], Cz = p[8];
    const float Ox = p[9], Oy = p[10], Oz = p[11];
    const float bx = Ax - Nx, by = Ay - Ny, bz = Az - Nz;
    const float cx = Cx - Ax, cy = Cy - Ay, cz = Cz - Az;
    const float axv = by * cz - bz * cy;
    const float ayv = bz * cx - bx * cz;
    const float azv = bx * cy - by * cx;
    dst[0] = Nx;  dst[1] = Ny;  dst[2] = Nz;
    dst[3] = Ax;  dst[4] = Ay;  dst[5] = Az;
    dst[6] = Cx;  dst[7] = Cy;  dst[8] = Cz;
    dst[9] = Ox;  dst[10] = Oy; dst[11] = Oz;
    dst[12] = -0.58273431f * axv + 0.56802827f * bx + -0.54067466f * cx + Ax;
    dst[13] = -0.58273431f * ayv + 0.56802827f * by + -0.54067466f * cy + Ay;
    dst[14] = -0.58273431f * azv + 0.56802827f * bz + -0.54067466f * cz + Az;
}

#define FS 432   // fp8 bytes/row; mult of 16 (aligned int4 rbf stores); 108 dw % 32 = 12

__device__ __forceinline__ int pk4(float a, float b, float c, float d) {
    int r = __builtin_amdgcn_cvt_pk_fp8_f32(a, b, 0, false);
    return __builtin_amdgcn_cvt_pk_fp8_f32(c, d, r, true);
}

__device__ __forceinline__ void compute_features(
    int tid, int Ri, int Ci,
    const float* __restrict__ W_pos, const float* __restrict__ b_pos,
    const int* jR, const int* jC,
    const float (*natoms)[15], const float* iatoms,
    unsigned char* featF8) {
    {
        const int e = tid >> 4, p = tid & 15;
        const int drel = jR[e] - Ri;
        const int same = (jC[e] == Ci);
        int dc = drel + 32;
        dc = dc < 0 ? 0 : (dc > 64 ? 64 : dc);
        const int df = same ? dc : 65;
        const float v = W_pos[p * 66 + df] + b_pos[p];
        const int pb = __builtin_amdgcn_cvt_pk_fp8_f32(v, 0.0f, 0, false);
        featF8[e * FS + p] = (unsigned char)(pb & 0xFF);
    }
#pragma unroll
    for (int it = 0; it < 2; ++it) {
        const int task = tid + it * 512;
        if (task < 800) {
            const int mn = task >> 5, e = task & 31;
            const int m = mn / 5, n = mn - m * 5;
            const float ax = iatoms[m * 3 + 0];
            const float ay = iatoms[m * 3 + 1];
            const float az = iatoms[m * 3 + 2];
            const float* na = &natoms[e][n * 3];
            const float dx = ax - na[0], dy = ay - na[1], dz = az - na[2];
            const float D = sqrtf(dx * dx + dy * dy + dz * dz + 1e-6f);
            int pk[4];
#pragma unroll
            for (int qq = 0; qq < 4; ++qq) {
                float v[4];
#pragma unroll
                for (int u = 0; u < 4; ++u) {
                    const int r = qq * 4 + u;
                    const float mu = (float)(2.0 + (double)r * (20.0 / 15.0));
                    const float t = D - mu;
                    v[u] = __expf(-(t * t) * (1.0f / 1.5625f));
                }
                pk[qq] = pk4(v[0], v[1], v[2], v[3]);
            }
            int4 w4; w4.x = pk[0]; w4.y = pk[1]; w4.z = pk[2]; w4.w = pk[3];
            *(int4*)(featF8 + e * FS + 16 + mn * 16) = w4;
        }
    }
}

__global__ __launch_bounds__(512, 6) void edge_kernel(
    const float* __restrict__ X,
    const int* __restrict__ Ridx, const int* __restrict__ Chain,
    const float* __restrict__ W_pos, const float* __restrict__ b_pos,
    const unsigned char* __restrict__ Wf8,
    const float* __restrict__ lng, const float* __restrict__ lnb,
    const float* __restrict__ eidx_f, float* __restrict__ outE) {
    const int tid = threadIdx.x;
    const int row0 = blockIdx.x * 4;
    const int b = row0 >> 11;                 // 2048 % 4 == 0: no batch straddle
    const int i0 = row0 & (LEN - 1);

    __shared__ __align__(16) unsigned char featF8[32 * FS]; // 13824 B
    __shared__ __align__(16) float hbuf[32 * 132];          // 16896 B
    __shared__ float natoms[4][32][15];                     //  7680 B
    __shared__ float iatoms[4][16];                         //   256 B
    __shared__ int jR[4][KNB], jC[4][KNB];                  //  1024 B
    __shared__ int riS[4], ciS[4];                          //    32 B

    const float* Xb = X + (size_t)b * LEN * 12;

    // --- W register residency (fp8): wave w owns channels w*16 + lr
    const int w = tid >> 6, l = tid & 63, lr = l & 15, lg = l >> 4;
    long wreg[13];
    {
        const unsigned char* wb = Wf8 + (size_t)(w * 16 + lr) * 416 + lg * 8;
#pragma unroll
        for (int ks = 0; ks < 13; ++ks)
            wreg[ks] = *(const long*)(wb + ks * 32);
    }

    // --- prologue: ALL 4 rows' gathers in parallel (hoisted off row loop)
    if (tid < 128) {
        const int r = tid >> 5, e = tid & 31;
        const int j = (int)eidx_f[(size_t)(row0 + r) * KNB + e];
        jR[r][e] = Ridx[b * LEN + j];
        jC[r][e] = Chain[b * LEN + j];
        load_res_atoms(Xb + j * 12, &natoms[r][e][0]);
    } else if (tid < 132) {
        const int r = tid - 128;
        load_res_atoms(Xb + (size_t)(i0 + r) * 12, &iatoms[r][0]);
    } else if (tid < 136) {
        riS[tid - 132] = Ridx[b * LEN + i0 + (tid - 132)];
    } else if (tid < 140) {
        ciS[tid - 136] = Chain[b * LEN + i0 + (tid - 136)];
    }
    __syncthreads();

    compute_features(tid, riS[0], ciS[0], W_pos, b_pos,
                     jR[0], jC[0], natoms[0], iatoms[0], featF8);
    __syncthreads();

    for (int r = 0; r < 4; ++r) {
        const int row = row0 + r;

        // === region B: fp8 GEMM(r) + scatter acc -> hbuf ===
        f32x4 acc0 = {0.f, 0.f, 0.f, 0.f}, acc1 = acc0;
        {
            const unsigned char* fb0 = featF8 + lr * FS + lg * 8;
            const unsigned char* fb1 = featF8 + (16 + lr) * FS + lg * 8;
#pragma unroll
            for (int ks = 0; ks < 13; ++ks) {
                const long a0 = *(const long*)(fb0 + ks * 32);
                const long a1 = *(const long*)(fb1 + ks * 32);
                acc0 = __builtin_amdgcn_mfma_f32_16x16x32_fp8_fp8(a0, wreg[ks], acc0, 0, 0, 0);
                acc1 = __builtin_amdgcn_mfma_f32_16x16x32_fp8_fp8(a1, wreg[ks], acc1, 0, 0, 0);
            }
        }
#pragma unroll
        for (int rr = 0; rr < 4; ++rr) {
            hbuf[(lg * 4 + rr) * 132 + w * 16 + lr]      = acc0[rr];
            hbuf[(16 + lg * 4 + rr) * 132 + w * 16 + lr] = acc1[rr];
        }
        __syncthreads();

        // === region C: LN(r) from hbuf + store; features(r+1) ===
        {
            const int g = tid >> 4, l2 = tid & 15;
            const float4* hb4 = (const float4*)(hbuf + g * 132 + l2 * 8);
            const float4 v0 = hb4[0], v1 = hb4[1];
            float s = v0.x + v0.y + v0.z + v0.w + v1.x + v1.y + v1.z + v1.w;
            float ssq = v0.x * v0.x + v0.y * v0.y + v0.z * v0.z + v0.w * v0.w
                      + v1.x * v1.x + v1.y * v1.y + v1.z * v1.z + v1.w * v1.w;
#pragma unroll
            for (int off = 1; off < 16; off <<= 1) {
                s += __shfl_xor(s, off, 64);
                ssq += __shfl_xor(ssq, off, 64);
            }
            const float mean = s * (1.0f / 128.0f);
            const float rstd = rsqrtf(ssq * (1.0f / 128.0f) - mean * mean + 1e-5f);

            float4* ob = (float4*)(outE + ((size_t)row * KNB + g) * HID + l2 * 8);
            const float4 g0 = *(const float4*)(lng + l2 * 8);
            const float4 g1 = *(const float4*)(lng + l2 * 8 + 4);
            const float4 b0 = *(const float4*)(lnb + l2 * 8);
            const float4 b1 = *(const float4*)(lnb + l2 * 8 + 4);
            float4 o0, o1;
            o0.x = (v0.x - mean) * rstd * g0.x + b0.x;
            o0.y = (v0.y - mean) * rstd * g0.y + b0.y;
            o0.z = (v0.z - mean) * rstd * g0.z + b0.z;
            o0.w = (v0.w - mean) * rstd * g0.w + b0.w;
            o1.x = (v1.x - mean) * rstd * g1.x + b1.x;
            o1.y = (v1.y - mean) * rstd * g1.y + b1.y;
            o1.z = (v1.z - mean) * rstd * g1.z + b1.z;
            o1.w = (v1.w - mean) * rstd * g1.w + b1.w;
            ob[0] = o0;
            ob[1] = o1;
        }
        if (r < 3) {
            compute_features(tid, riS[r + 1], ciS[r + 1], W_pos, b_pos,
                             jR[r + 1], jC[r + 1], natoms[r + 1], iatoms[r + 1],
                             featF8);
        }
        __syncthreads();
    }
}

extern "C" void kernel_launch(void* const* d_in, const int* in_sizes, int n_in,
                              void* d_out, int out_size, void* d_ws, size_t ws_size,
                              hipStream_t stream) {
    const float* X      = (const float*)d_in[0];
    const float* mask   = (const float*)d_in[1];
    const int*   Ridx   = (const int*)d_in[2];
    const int*   Chain  = (const int*)d_in[3];
    const float* W_pos  = (const float*)d_in[4];
    const float* b_pos  = (const float*)d_in[5];
    const float* W_edge = (const float*)d_in[6];
    const float* lng    = (const float*)d_in[7];
    const float* lnb    = (const float*)d_in[8];

    float* out  = (float*)d_out;
    float* eidx = out;                           // B*L*K floats (exact ints)
    float* E    = out + (size_t)2 * LEN * KNB;   // B*L*K*HID floats

    float4* CAm = (float4*)d_ws;                                  // 64 KiB
    unsigned char* Wf8 = (unsigned char*)d_ws + 2 * LEN * 16;     // 52 KiB

    const int nrow = 2 * LEN;
    prep_kernel<<<52, 256, 0, stream>>>(X, mask, W_edge, CAm, (int*)Wf8);
    topk_kernel<<<nrow, 256, 0, stream>>>(CAm, eidx);
    edge_kernel<<<nrow / 4, 512, 0, stream>>>(X, Ridx, Chain, W_pos, b_pos, Wf8,
                                              lng, lnb, eidx, E);
}